// Round 15
// baseline (273.725 us; speedup 1.0000x reference)
//
#include <hip/hip_runtime.h>
#include <cstdint>
#include <cstddef>

typedef unsigned short u16;
typedef unsigned int u32;
typedef __bf16 bf16x8 __attribute__((ext_vector_type(8)));
typedef float f32x4 __attribute__((ext_vector_type(4)));
typedef float f32x16 __attribute__((ext_vector_type(16)));

__device__ __forceinline__ u16 f2bf(float f) {
  unsigned u = __builtin_bit_cast(unsigned, f);
  return (u16)((u + 0x7FFFu + ((u >> 16) & 1u)) >> 16);
}

// native pack: compiler emits v_cvt_pk_bf16_f32
__device__ __forceinline__ u32 pk2bf(float lo, float hi) {
  union { __bf16 h[2]; u32 u; } t;
  t.h[0] = (__bf16)lo; t.h[1] = (__bf16)hi;
  return t.u;
}

__device__ __forceinline__ void gl_lds16(const void* g, void* l) {
  __builtin_amdgcn_global_load_lds(
      (const __attribute__((address_space(1))) unsigned int*)g,
      (__attribute__((address_space(3))) unsigned int*)l,
      16, 0, 0);
}

// fused fp32 -> bf16 cast of x (2097152 float4), Wqkv (786432), Wlift (262144)
__global__ void cast_all_kernel(const float* __restrict__ x, u16* __restrict__ xo,
                                const float* __restrict__ wq, u16* __restrict__ wqo,
                                const float* __restrict__ wl, u16* __restrict__ wlo) {
  int i = blockIdx.x * blockDim.x + threadIdx.x;
  const float* src;
  u16* dst;
  int k;
  if (i < 2097152) { src = x; dst = xo; k = i; }
  else if (i < 2883584) { src = wq; dst = wqo; k = i - 2097152; }
  else { src = wl; dst = wlo; k = i - 2883584; }
  float4 v = reinterpret_cast<const float4*>(src)[k];
  ushort4 o;
  o.x = f2bf(v.x); o.y = f2bf(v.y); o.z = f2bf(v.z); o.w = f2bf(v.w);
  reinterpret_cast<ushort4*>(dst)[k] = o;
}

// ---------------------------------------------------------------------------
// QKV GEMM: C = A(8192x1024) * B^T(3072x1024), 256x256 tile, BK=64, 8 waves
// (2M x 4N), double-buffered 128KB LDS, 4 quadrant-phases per K-tile:
// {12 swizzled ds_read_b128 -> lgkmcnt(0) -> 16 MFMA}, 8 global_load_lds
// issued at phase 0, ONE vmcnt(0)+barrier per K-tile (issue-to-wait distance
// ~4 phases >> HBM latency). Swizzle: byte ^= (row&7)<<4 both-sides.
// XCD-grouped: 48 blocks/XCD, brow-fastest within bcol group (B-panel x4,
// A-panels 2MB L2-resident). Epilogue: qkv scatter (q prescaled, V transp).
// ---------------------------------------------------------------------------
__global__ __launch_bounds__(512, 2)
void gemm256_qkv_kernel(const u16* __restrict__ A, const u16* __restrict__ Bw,
                        const float* __restrict__ bias,
                        u16* __restrict__ oq, u16* __restrict__ ok,
                        u16* __restrict__ ovT) {
  __shared__ __align__(16) u16 Als[2][256 * 64];
  __shared__ __align__(16) u16 Bls[2][256 * 64];

  const int tid = threadIdx.x, lane = tid & 63;
  const int w = tid >> 6, wr = w >> 2, wc = w & 3;   // 2M x 4N wave grid
  const int lr = lane & 15, lk = lane >> 4;

  // XCD-grouped mapping: 384 blocks, 48/XCD = 12 bcol-groups x 4 brow
  const int local = blockIdx.x >> 3, x = blockIdx.x & 7;
  const int bcol = (local >> 2) * 256;
  const int brow = (x * 4 + (local & 3)) * 256;

  // staging: 4 slots per operand per thread; slot s: row=s>>3, chunk=s&7,
  // source chunk pre-swizzled = chunk ^ (row&7) (both-sides rule)
  const u16* ga[4];
  const u16* gb[4];
  int dsl[4];
#pragma unroll
  for (int p = 0; p < 4; ++p) {
    const int s = tid + p * 512;
    const int row = s >> 3, ch = s & 7;
    const int sc = ch ^ (row & 7);
    ga[p] = A + (size_t)(brow + row) * 1024 + sc * 8;
    gb[p] = Bw + (size_t)(bcol + row) * 1024 + sc * 8;
    dsl[p] = s * 8;
  }

  auto stage = [&](int buf, int kt) {
#pragma unroll
    for (int p = 0; p < 4; ++p) {
      gl_lds16(ga[p] + kt * 64, &Als[buf][dsl[p]]);
      gl_lds16(gb[p] + kt * 64, &Bls[buf][dsl[p]]);
    }
  };

  f32x4 acc[2][2][4][2] = {};

  stage(0, 0);
  asm volatile("s_waitcnt vmcnt(0)" ::: "memory");
  __builtin_amdgcn_s_barrier();
  __builtin_amdgcn_sched_barrier(0);

  for (int t = 0; t < 16; ++t) {
    const int buf = t & 1;
    const char* Ab = (const char*)&Als[buf][0];
    const char* Bb = (const char*)&Bls[buf][0];
    if (t + 1 < 16) stage(buf ^ 1, t + 1);   // 8 loads, waited at iter end
#pragma unroll
    for (int mq = 0; mq < 2; ++mq)
#pragma unroll
      for (int nq = 0; nq < 2; ++nq) {
        // ---- phase (mq,nq): frag reads for this quadrant ----
        bf16x8 af[4][2], bfr[2][2];
#pragma unroll
        for (int m = 0; m < 4; ++m) {
          const int ar = wr * 128 + mq * 64 + m * 16 + lr;
          const int asw = (ar & 7) << 4;
#pragma unroll
          for (int ks = 0; ks < 2; ++ks)
            af[m][ks] = *reinterpret_cast<const bf16x8*>(
                Ab + ar * 128 + ((ks * 64 + lk * 16) ^ asw));
        }
#pragma unroll
        for (int n = 0; n < 2; ++n) {
          const int br = wc * 64 + nq * 32 + n * 16 + lr;
          const int bsw = (br & 7) << 4;
#pragma unroll
          for (int ks = 0; ks < 2; ++ks)
            bfr[n][ks] = *reinterpret_cast<const bf16x8*>(
                Bb + br * 128 + ((ks * 64 + lk * 16) ^ bsw));
        }
        asm volatile("s_waitcnt lgkmcnt(0)" ::: "memory");
        __builtin_amdgcn_sched_barrier(0);
        __builtin_amdgcn_s_setprio(1);
#pragma unroll
        for (int ks = 0; ks < 2; ++ks)
#pragma unroll
          for (int m = 0; m < 4; ++m)
#pragma unroll
            for (int n = 0; n < 2; ++n)
              acc[mq][nq][m][n] = __builtin_amdgcn_mfma_f32_16x16x32_bf16(
                  af[m][ks], bfr[n][ks], acc[mq][nq][m][n], 0, 0, 0);
        __builtin_amdgcn_s_setprio(0);
      }
    asm volatile("s_waitcnt vmcnt(0)" ::: "memory");
    __builtin_amdgcn_s_barrier();
    __builtin_amdgcn_sched_barrier(0);
  }

  // ---- epilogue: qkv scatter ----
  const int three = bcol >> 10;   // 0=q, 1=k, 2=v (bcol multiple of 256)
#pragma unroll
  for (int mq = 0; mq < 2; ++mq)
#pragma unroll
    for (int nq = 0; nq < 2; ++nq)
#pragma unroll
      for (int n = 0; n < 2; ++n) {
        const int c = bcol + wc * 64 + nq * 32 + n * 16 + lr;
        const float bv = bias[c];
        const int cc = c & 1023, h = cc >> 6, hd = cc & 63;
#pragma unroll
        for (int m = 0; m < 4; ++m) {
          const int r0 = brow + wr * 128 + mq * 64 + m * 16 + lk * 4;
          const int b = r0 >> 11;
          const int s0 = r0 & 2047;
          const f32x4& a4 = acc[mq][nq][m][n];
          if (three == 2) {
            ushort4 pkv;
            pkv.x = f2bf(a4[0] + bv);
            pkv.y = f2bf(a4[1] + bv);
            pkv.z = f2bf(a4[2] + bv);
            pkv.w = f2bf(a4[3] + bv);
            *reinterpret_cast<ushort4*>(
                &ovT[((size_t)(b * 16 + h) * 64 + hd) * 2048 + s0]) = pkv;
          } else {
            u16* dst = (three == 0) ? oq : ok;
            // q prescale: SCALE * log2(e) so attention uses raw v_exp (2^x)
            const float sc = (three == 0) ? 0.03125f * 1.44269504089f : 1.0f;
#pragma unroll
            for (int j = 0; j < 4; ++j)
              dst[((size_t)(b * 16 + h) * 2048 + (s0 + j)) * 64 + hd] =
                  f2bf((a4[j] + bv) * sc);
          }
        }
      }
}

// lift GEMM: C = A(MxK) * B^T(NxK) + bias, fp32 out. 128x128 tile, BK=32,
// XCD-grouped 1D grid (r14-verified).
__global__ __launch_bounds__(256)
void gemm_lift_kernel(const u16* __restrict__ A, const u16* __restrict__ Bw,
                      const float* __restrict__ bias, float* __restrict__ ofp,
                      int M, int N, int K) {
  __shared__ __align__(16) u16 Als[2][128 * 32];
  __shared__ __align__(16) u16 Bls[2][128 * 32];

  const int tid = threadIdx.x;
  const int lane = tid & 63;
  const int w = tid >> 6, wr = w >> 1, wc = w & 1;
  const int lr = lane & 15, lk = lane >> 4;

  const int nbx = N >> 7;
  const int nb = (M >> 7) * nbx;
  const int vb = (blockIdx.x & 7) * (nb >> 3) + (blockIdx.x >> 3);
  const int brow = (vb / nbx) * 128, bcol = (vb % nbx) * 128;

  const int srow = tid >> 2;
  const int scol = (tid & 3) << 3;
  const u16* ga = A + (size_t)(brow + srow) * K + scol;
  const u16* gb = Bw + (size_t)(bcol + srow) * K + scol;

  f32x4 acc[4][4] = {};

  auto stage = [&](int buf, int kt) {
    const u16* a0 = ga + kt * 32;
    const u16* b0 = gb + kt * 32;
    gl_lds16(a0,             &Als[buf][tid * 8]);
    gl_lds16(a0 + 64 * K,    &Als[buf][2048 + tid * 8]);
    gl_lds16(b0,             &Bls[buf][tid * 8]);
    gl_lds16(b0 + 64 * K,    &Bls[buf][2048 + tid * 8]);
  };

  stage(0, 0);
  __syncthreads();

  const int nt = K >> 5;
  int cur = 0;
  for (int t = 0; t < nt; ++t) {
    if (t + 1 < nt) stage(cur ^ 1, t + 1);
    bf16x8 af[4], bfr[4];
#pragma unroll
    for (int m = 0; m < 4; ++m)
      af[m] = *reinterpret_cast<const bf16x8*>(&Als[cur][(wr * 64 + m * 16 + lr) * 32 + lk * 8]);
#pragma unroll
    for (int n = 0; n < 4; ++n)
      bfr[n] = *reinterpret_cast<const bf16x8*>(&Bls[cur][(wc * 64 + n * 16 + lr) * 32 + lk * 8]);
#pragma unroll
    for (int m = 0; m < 4; ++m)
#pragma unroll
      for (int n = 0; n < 4; ++n)
        acc[m][n] = __builtin_amdgcn_mfma_f32_16x16x32_bf16(af[m], bfr[n], acc[m][n], 0, 0, 0);
    __syncthreads();
    cur ^= 1;
  }

#pragma unroll
  for (int n = 0; n < 4; ++n) {
    const int c = bcol + wc * 64 + n * 16 + lr;
    const float bv = bias[c];
#pragma unroll
    for (int m = 0; m < 4; ++m) {
      const int r0 = brow + wr * 64 + m * 16 + lk * 4;
#pragma unroll
      for (int j = 0; j < 4; ++j)
        ofp[(size_t)(r0 + j) * N + c] = acc[m][n][j] + bv;
    }
  }
}

// Causal flash attention, swapped-QK^T 32x32x16 — EXACT r10 config (best
// measured: 165.7us): LPT heavy-first mapping, PV pipelined one slab behind
// (named pending regs), triple-buffered LDS, stage 2 tiles ahead with
// clamped dummy re-stages, counted vmcnt(4) barriers.
__global__ __launch_bounds__(256, 3)
void attn_causal_kernel(const u16* __restrict__ qg, const u16* __restrict__ kg_,
                        const u16* __restrict__ vT, u16* __restrict__ ob) {
  __shared__ __align__(16) u16 Kls[3][64 * 64];
  __shared__ __align__(16) u16 Vls[3][64 * 64];

  const int tid = threadIdx.x, lane = tid & 63, w = tid >> 6;  // w 0..3
  const int n = lane & 31, hi = lane >> 5;
  const int bid = blockIdx.x;
  const int qbi = 15 - (bid >> 6);       // heavy-first (LPT)
  const int bh = bid & 63;
  const int q0w = qbi * 128 + w * 32;
  const int jdiag = qbi * 4 + w;         // wave's diagonal slab index
  const size_t base = (size_t)bh * 2048 * 64;
  const size_t vbase = (size_t)bh * 64 * 2048;

  // Q fragments: B-operand of mfma(K,Q): lane holds Q[q0w+n][dc*16+hi*8 .. +7]
  bf16x8 qf[4];
#pragma unroll
  for (int dc = 0; dc < 4; ++dc)
    qf[dc] = *reinterpret_cast<const bf16x8*>(
        &qg[base + (size_t)(q0w + n) * 64 + dc * 16 + hi * 8]);

  f32x16 o0 = {}, o1 = {};
  float l = 0.f;

  const int ktiles = qbi * 2 + 2;

  // staging: 2 passes x 256 lanes x 16B per operand per 64-tile (r3-verified)
  const int krow = tid >> 3, kch = tid & 7;

  auto stage = [&](int buf, int t) {
    const int k0 = t << 6;
#pragma unroll
    for (int p = 0; p < 2; ++p) {
      const int r = p * 32 + krow;
      const int sz = (r ^ (r >> 3)) & 7;
      gl_lds16(kg_ + base + (size_t)(k0 + r) * 64 + (kch ^ sz) * 8,
               &Kls[buf][p * 2048 + tid * 8]);
      gl_lds16(vT + vbase + (size_t)r * 2048 + k0 + (kch ^ sz) * 8,
               &Vls[buf][p * 2048 + tid * 8]);
    }
  };

  // loop-invariant read-side swizzle terms (rows n and 32+n)
  const int sw0 = ((n ^ (n >> 3)) & 7) << 4;
  const int sw1 = (((32 + n) ^ ((32 + n) >> 3)) & 7) << 4;

  // ---- prologue: stage tiles 0,1; wait oldest 4 (tile 0) ----
  stage(0, 0);
  stage(1, ktiles > 1 ? 1 : 0);
  asm volatile("s_waitcnt vmcnt(4)" ::: "memory");
  __builtin_amdgcn_sched_barrier(0);
  __builtin_amdgcn_s_barrier();
  __builtin_amdgcn_sched_barrier(0);

  // pending-PV state: NAMED registers (rule #20)
  bf16x8 pbP0 = {}, pbP1 = {}, vfP00 = {}, vfP01 = {}, vfP10 = {}, vfP11 = {};
  bool pend = false;

  union U { u32 u[4]; bf16x8 v; };

  // one 32-key slab, PV pipelined one slab behind
  auto slab = [&](const char* Kb, const char* Vb, int mt, bool diag) {
    const int swK = mt ? sw1 : sw0;
    f32x16 st = {};
    __builtin_amdgcn_s_setprio(1);
#pragma unroll
    for (int dc = 0; dc < 4; ++dc) {
      bf16x8 kf = *reinterpret_cast<const bf16x8*>(
          Kb + (mt * 32 + n) * 128 + ((((dc << 1) | hi) << 4) ^ swK));
      st = __builtin_amdgcn_mfma_f32_32x32x16_bf16(kf, qf[dc], st, 0, 0, 0);
    }
    // pending PV of slab e-1: independent of st chain, fills MFMA pipe
    if (pend) {
      o0 = __builtin_amdgcn_mfma_f32_32x32x16_bf16(vfP00, pbP0, o0, 0, 0, 0);
      o1 = __builtin_amdgcn_mfma_f32_32x32x16_bf16(vfP01, pbP0, o1, 0, 0, 0);
      o0 = __builtin_amdgcn_mfma_f32_32x32x16_bf16(vfP10, pbP1, o0, 0, 0, 0);
      o1 = __builtin_amdgcn_mfma_f32_32x32x16_bf16(vfP11, pbP1, o1, 0, 0, 0);
    }
    __builtin_amdgcn_s_setprio(0);
    if (diag) {
#pragma unroll
      for (int r = 0; r < 16; ++r) {
        const int koff = (r & 3) + 8 * (r >> 2) + 4 * hi;
        if (koff > n) st[r] = -1e30f;
      }
    }
    float rs = 0.f;
#pragma unroll
    for (int r = 0; r < 16; ++r) { st[r] = __builtin_amdgcn_exp2f(st[r]); rs += st[r]; }
    l += rs;
    // pack this slab's P into the pending regs (pend PV already consumed old)
#pragma unroll
    for (int kk = 0; kk < 2; ++kk) {
      const int gown = (kk * 2 + hi) * 4, gsnd = (kk * 2 + (hi ^ 1)) * 4;
      u32 pa0 = pk2bf(st[gown + 0], st[gown + 1]);
      u32 pa1 = pk2bf(st[gown + 2], st[gown + 3]);
      u32 ps0 = pk2bf(st[gsnd + 0], st[gsnd + 1]);
      u32 ps1 = pk2bf(st[gsnd + 2], st[gsnd + 3]);
      u32 rA = __shfl_xor(ps0, 32, 64);
      u32 rB = __shfl_xor(ps1, 32, 64);
      U pb;
      pb.u[0] = hi ? rA : pa0;
      pb.u[1] = hi ? rB : pa1;
      pb.u[2] = hi ? pa0 : rA;
      pb.u[3] = hi ? pa1 : rB;
      if (kk == 0) pbP0 = pb.v; else pbP1 = pb.v;
    }
    // V fragments for this slab into pending regs (off the critical chain)
    const int c0 = ((mt * 4 + hi) << 4);
    const int c1 = ((mt * 4 + 2 + hi) << 4);
    vfP00 = *reinterpret_cast<const bf16x8*>(Vb + n * 128 + (c0 ^ sw0));
    vfP01 = *reinterpret_cast<const bf16x8*>(Vb + (32 + n) * 128 + (c0 ^ sw1));
    vfP10 = *reinterpret_cast<const bf16x8*>(Vb + n * 128 + (c1 ^ sw0));
    vfP11 = *reinterpret_cast<const bf16x8*>(Vb + (32 + n) * 128 + (c1 ^ sw1));
    pend = true;
  };

  for (int t = 0; t < ktiles; ++t) {
    // stage 2 ahead; clamp to last tile (dummy re-stage) so exactly 8 loads
    // are always outstanding -> vmcnt(4) is uniformly correct
    const int tpre = (t + 2 < ktiles) ? (t + 2) : (ktiles - 1);
    stage((t + 2) % 3, tpre);
    const char* Kb = (const char*)&Kls[t % 3][0];
    const char* Vb = (const char*)&Vls[t % 3][0];
    const int e0 = 2 * t;
    if (e0 <= jdiag) slab(Kb, Vb, 0, e0 == jdiag);
    if (e0 + 1 <= jdiag) slab(Kb, Vb, 1, e0 + 1 == jdiag);
    asm volatile("s_waitcnt vmcnt(4)" ::: "memory");
    __builtin_amdgcn_sched_barrier(0);
    __builtin_amdgcn_s_barrier();
    __builtin_amdgcn_sched_barrier(0);
  }

  // flush the last pending PV
  if (pend) {
    __builtin_amdgcn_s_setprio(1);
    o0 = __builtin_amdgcn_mfma_f32_32x32x16_bf16(vfP00, pbP0, o0, 0, 0, 0);
    o1 = __builtin_amdgcn_mfma_f32_32x32x16_bf16(vfP01, pbP0, o1, 0, 0, 0);
    o0 = __builtin_amdgcn_mfma_f32_32x32x16_bf16(vfP10, pbP1, o0, 0, 0, 0);
    o1 = __builtin_amdgcn_mfma_f32_32x32x16_bf16(vfP11, pbP1, o1, 0, 0, 0);
    __builtin_amdgcn_s_setprio(0);
  }

  // drain LDS-DMA before workgroup teardown (dummy stages may be in flight)
  asm volatile("s_waitcnt vmcnt(0)" ::: "memory");

  // ---- epilogue: O^T C-layout -> ob[b][s][h*64+d], normalize ----
  const int b = bh >> 4, h = bh & 15;
  const float lt = l + __shfl_xor(l, 32, 64);
  const float inv = 1.f / lt;
  const size_t rbase = ((size_t)(b * 2048 + q0w + n)) * 1024 + h * 64;
#pragma unroll
  for (int g = 0; g < 4; ++g) {
    ushort4 w0, w1;
    w0.x = f2bf(o0[g * 4 + 0] * inv); w0.y = f2bf(o0[g * 4 + 1] * inv);
    w0.z = f2bf(o0[g * 4 + 2] * inv); w0.w = f2bf(o0[g * 4 + 3] * inv);
    w1.x = f2bf(o1[g * 4 + 0] * inv); w1.y = f2bf(o1[g * 4 + 1] * inv);
    w1.z = f2bf(o1[g * 4 + 2] * inv); w1.w = f2bf(o1[g * 4 + 3] * inv);
    *reinterpret_cast<ushort4*>(&ob[rbase + g * 8 + hi * 4]) = w0;
    *reinterpret_cast<ushort4*>(&ob[rbase + 32 + g * 8 + hi * 4]) = w1;
  }
}

extern "C" void kernel_launch(void* const* d_in, const int* in_sizes, int n_in,
                              void* d_out, int out_size, void* d_ws, size_t ws_size,
                              hipStream_t stream) {
  const float* x     = (const float*)d_in[0];
  const float* Wqkv  = (const float*)d_in[1];
  const float* bqkv  = (const float*)d_in[2];
  const float* Wlift = (const float*)d_in[3];
  const float* blift = (const float*)d_in[4];
  float* out = (float*)d_out;

  if (ws_size < 40ull * 1024 * 1024) return;

  char* ws = (char*)d_ws;
  u16* xb     = (u16*)(ws);                        // 16 MB; reused as attn output
  u16* wqkvb  = (u16*)(ws + 16777216);             // 6 MB
  u16* wliftb = (u16*)(ws + 23068672);             // 2 MB
  u16* vT     = (u16*)(ws + 25165824);             // 16 MB
  u16* attnb  = xb;
  u16* qb = (u16*)d_out;                           // q/k in d_out (dead before lift GEMM)
  u16* kb = qb + 8388608;

  cast_all_kernel<<<12288, 256, 0, stream>>>(x, xb, Wqkv, wqkvb, Wlift, wliftb);

  gemm256_qkv_kernel<<<384, 512, 0, stream>>>(xb, wqkvb, bqkv, qb, kb, vT);

  attn_causal_kernel<<<1024, 256, 0, stream>>>(qb, kb, vT, attnb);

  gemm_lift_kernel<<<512, 256, 0, stream>>>(
      attnb, wliftb, blift, out, 8192, 1024, 1024);
}

// Round 16
// 259.268 us; speedup vs baseline: 1.0558x; 1.0558x over previous
//
#include <hip/hip_runtime.h>
#include <cstdint>
#include <cstddef>

typedef unsigned short u16;
typedef unsigned int u32;
typedef __bf16 bf16x8 __attribute__((ext_vector_type(8)));
typedef float f32x4 __attribute__((ext_vector_type(4)));
typedef float f32x16 __attribute__((ext_vector_type(16)));

__device__ __forceinline__ u16 f2bf(float f) {
  unsigned u = __builtin_bit_cast(unsigned, f);
  return (u16)((u + 0x7FFFu + ((u >> 16) & 1u)) >> 16);
}

// native pack: compiler emits v_cvt_pk_bf16_f32
__device__ __forceinline__ u32 pk2bf(float lo, float hi) {
  union { __bf16 h[2]; u32 u; } t;
  t.h[0] = (__bf16)lo; t.h[1] = (__bf16)hi;
  return t.u;
}

__device__ __forceinline__ void gl_lds16(const void* g, void* l) {
  __builtin_amdgcn_global_load_lds(
      (const __attribute__((address_space(1))) unsigned int*)g,
      (__attribute__((address_space(3))) unsigned int*)l,
      16, 0, 0);
}

// fused fp32 -> bf16 cast of x (2097152 float4), Wqkv (786432), Wlift (262144)
__global__ void cast_all_kernel(const float* __restrict__ x, u16* __restrict__ xo,
                                const float* __restrict__ wq, u16* __restrict__ wqo,
                                const float* __restrict__ wl, u16* __restrict__ wlo) {
  int i = blockIdx.x * blockDim.x + threadIdx.x;
  const float* src;
  u16* dst;
  int k;
  if (i < 2097152) { src = x; dst = xo; k = i; }
  else if (i < 2883584) { src = wq; dst = wqo; k = i - 2097152; }
  else { src = wl; dst = wlo; k = i - 2883584; }
  float4 v = reinterpret_cast<const float4*>(src)[k];
  ushort4 o;
  o.x = f2bf(v.x); o.y = f2bf(v.y); o.z = f2bf(v.z); o.w = f2bf(v.w);
  reinterpret_cast<ushort4*>(dst)[k] = o;
}

// C = A(MxK) * B^T(NxK), bf16 operands, fp32 accum. 128x128 tile, BK=32.
// 1D grid with XCD-grouped mapping (T1): xcd = bid&7 owns a contiguous
// brow range (8 A-panels = 2MB, L2-resident); consecutive blocks within an
// XCD share the A panel (bcol-major walk).
template <int EPI>
__global__ __launch_bounds__(256)
void gemm_bt_kernel(const u16* __restrict__ A, const u16* __restrict__ Bw,
                    const float* __restrict__ bias,
                    u16* __restrict__ oq, u16* __restrict__ ok, u16* __restrict__ ovT,
                    float* __restrict__ ofp, int M, int N, int K) {
  __shared__ __align__(16) u16 Als[2][128 * 32];
  __shared__ __align__(16) u16 Bls[2][128 * 32];

  const int tid = threadIdx.x;
  const int lane = tid & 63;
  const int w = tid >> 6, wr = w >> 1, wc = w & 1;
  const int lr = lane & 15, lk = lane >> 4;

  // XCD-grouped block mapping (nblocks divisible by 8 for both GEMMs)
  const int nbx = N >> 7;
  const int nb = (M >> 7) * nbx;
  const int vb = (blockIdx.x & 7) * (nb >> 3) + (blockIdx.x >> 3);
  const int brow = (vb / nbx) * 128, bcol = (vb % nbx) * 128;

  const int srow = tid >> 2;
  const int scol = (tid & 3) << 3;
  const u16* ga = A + (size_t)(brow + srow) * K + scol;
  const u16* gb = Bw + (size_t)(bcol + srow) * K + scol;

  f32x4 acc[4][4] = {};

  auto stage = [&](int buf, int kt) {
    const u16* a0 = ga + kt * 32;
    const u16* b0 = gb + kt * 32;
    gl_lds16(a0,             &Als[buf][tid * 8]);
    gl_lds16(a0 + 64 * K,    &Als[buf][2048 + tid * 8]);
    gl_lds16(b0,             &Bls[buf][tid * 8]);
    gl_lds16(b0 + 64 * K,    &Bls[buf][2048 + tid * 8]);
  };

  stage(0, 0);
  __syncthreads();

  const int nt = K >> 5;
  int cur = 0;
  for (int t = 0; t < nt; ++t) {
    if (t + 1 < nt) stage(cur ^ 1, t + 1);
    bf16x8 af[4], bfr[4];
#pragma unroll
    for (int m = 0; m < 4; ++m)
      af[m] = *reinterpret_cast<const bf16x8*>(&Als[cur][(wr * 64 + m * 16 + lr) * 32 + lk * 8]);
#pragma unroll
    for (int n = 0; n < 4; ++n)
      bfr[n] = *reinterpret_cast<const bf16x8*>(&Bls[cur][(wc * 64 + n * 16 + lr) * 32 + lk * 8]);
#pragma unroll
    for (int m = 0; m < 4; ++m)
#pragma unroll
      for (int n = 0; n < 4; ++n)
        acc[m][n] = __builtin_amdgcn_mfma_f32_16x16x32_bf16(af[m], bfr[n], acc[m][n], 0, 0, 0);
    __syncthreads();
    cur ^= 1;
  }

  if (EPI == 0) {
    const int three = bcol >> 10;
#pragma unroll
    for (int n = 0; n < 4; ++n) {
      const int c = bcol + wc * 64 + n * 16 + lr;
      const float bv = bias[c];
      const int cc = c & 1023, h = cc >> 6, hd = cc & 63;
#pragma unroll
      for (int m = 0; m < 4; ++m) {
        const int r0 = brow + wr * 64 + m * 16 + lk * 4;
        const int b = r0 >> 11;
        const int s0 = r0 & 2047;
        if (three == 2) {
          ushort4 pkv;
          pkv.x = f2bf(acc[m][n][0] + bv);
          pkv.y = f2bf(acc[m][n][1] + bv);
          pkv.z = f2bf(acc[m][n][2] + bv);
          pkv.w = f2bf(acc[m][n][3] + bv);
          *reinterpret_cast<ushort4*>(&ovT[((size_t)(b * 16 + h) * 64 + hd) * 2048 + s0]) = pkv;
        } else {
          u16* dst = (three == 0) ? oq : ok;
          // q prescale: SCALE * log2(e) so attention uses raw v_exp (2^x)
          const float sc = (three == 0) ? 0.03125f * 1.44269504089f : 1.0f;
#pragma unroll
          for (int j = 0; j < 4; ++j)
            dst[((size_t)(b * 16 + h) * 2048 + (s0 + j)) * 64 + hd] = f2bf((acc[m][n][j] + bv) * sc);
        }
      }
    }
  } else {
#pragma unroll
    for (int n = 0; n < 4; ++n) {
      const int c = bcol + wc * 64 + n * 16 + lr;
      const float bv = bias[c];
#pragma unroll
      for (int m = 0; m < 4; ++m) {
        const int r0 = brow + wr * 64 + m * 16 + lk * 4;
#pragma unroll
        for (int j = 0; j < 4; ++j)
          ofp[(size_t)(r0 + j) * N + c] = acc[m][n][j] + bv;
      }
    }
  }
}

// Causal flash attention, swapped-QK^T 32x32x16 — EXACT r10 config (best
// measured: 165.7us): LPT heavy-first mapping, PV pipelined one slab behind
// (named pending regs), triple-buffered LDS, stage 2 tiles ahead with
// clamped dummy re-stages, counted vmcnt(4) barriers.
__global__ __launch_bounds__(256, 3)
void attn_causal_kernel(const u16* __restrict__ qg, const u16* __restrict__ kg_,
                        const u16* __restrict__ vT, u16* __restrict__ ob) {
  __shared__ __align__(16) u16 Kls[3][64 * 64];
  __shared__ __align__(16) u16 Vls[3][64 * 64];

  const int tid = threadIdx.x, lane = tid & 63, w = tid >> 6;  // w 0..3
  const int n = lane & 31, hi = lane >> 5;
  const int bid = blockIdx.x;
  const int qbi = 15 - (bid >> 6);       // heavy-first (LPT)
  const int bh = bid & 63;
  const int q0w = qbi * 128 + w * 32;
  const int jdiag = qbi * 4 + w;         // wave's diagonal slab index
  const size_t base = (size_t)bh * 2048 * 64;
  const size_t vbase = (size_t)bh * 64 * 2048;

  // Q fragments: B-operand of mfma(K,Q): lane holds Q[q0w+n][dc*16+hi*8 .. +7]
  bf16x8 qf[4];
#pragma unroll
  for (int dc = 0; dc < 4; ++dc)
    qf[dc] = *reinterpret_cast<const bf16x8*>(
        &qg[base + (size_t)(q0w + n) * 64 + dc * 16 + hi * 8]);

  f32x16 o0 = {}, o1 = {};
  float l = 0.f;

  const int ktiles = qbi * 2 + 2;

  // staging: 2 passes x 256 lanes x 16B per operand per 64-tile (r3-verified)
  const int krow = tid >> 3, kch = tid & 7;

  auto stage = [&](int buf, int t) {
    const int k0 = t << 6;
#pragma unroll
    for (int p = 0; p < 2; ++p) {
      const int r = p * 32 + krow;
      const int sz = (r ^ (r >> 3)) & 7;
      gl_lds16(kg_ + base + (size_t)(k0 + r) * 64 + (kch ^ sz) * 8,
               &Kls[buf][p * 2048 + tid * 8]);
      gl_lds16(vT + vbase + (size_t)r * 2048 + k0 + (kch ^ sz) * 8,
               &Vls[buf][p * 2048 + tid * 8]);
    }
  };

  // loop-invariant read-side swizzle terms (rows n and 32+n)
  const int sw0 = ((n ^ (n >> 3)) & 7) << 4;
  const int sw1 = (((32 + n) ^ ((32 + n) >> 3)) & 7) << 4;

  // ---- prologue: stage tiles 0,1; wait oldest 4 (tile 0) ----
  stage(0, 0);
  stage(1, ktiles > 1 ? 1 : 0);
  asm volatile("s_waitcnt vmcnt(4)" ::: "memory");
  __builtin_amdgcn_sched_barrier(0);
  __builtin_amdgcn_s_barrier();
  __builtin_amdgcn_sched_barrier(0);

  // pending-PV state: NAMED registers (rule #20)
  bf16x8 pbP0 = {}, pbP1 = {}, vfP00 = {}, vfP01 = {}, vfP10 = {}, vfP11 = {};
  bool pend = false;

  union U { u32 u[4]; bf16x8 v; };

  // one 32-key slab, PV pipelined one slab behind
  auto slab = [&](const char* Kb, const char* Vb, int mt, bool diag) {
    const int swK = mt ? sw1 : sw0;
    f32x16 st = {};
    __builtin_amdgcn_s_setprio(1);
#pragma unroll
    for (int dc = 0; dc < 4; ++dc) {
      bf16x8 kf = *reinterpret_cast<const bf16x8*>(
          Kb + (mt * 32 + n) * 128 + ((((dc << 1) | hi) << 4) ^ swK));
      st = __builtin_amdgcn_mfma_f32_32x32x16_bf16(kf, qf[dc], st, 0, 0, 0);
    }
    // pending PV of slab e-1: independent of st chain, fills MFMA pipe
    if (pend) {
      o0 = __builtin_amdgcn_mfma_f32_32x32x16_bf16(vfP00, pbP0, o0, 0, 0, 0);
      o1 = __builtin_amdgcn_mfma_f32_32x32x16_bf16(vfP01, pbP0, o1, 0, 0, 0);
      o0 = __builtin_amdgcn_mfma_f32_32x32x16_bf16(vfP10, pbP1, o0, 0, 0, 0);
      o1 = __builtin_amdgcn_mfma_f32_32x32x16_bf16(vfP11, pbP1, o1, 0, 0, 0);
    }
    __builtin_amdgcn_s_setprio(0);
    if (diag) {
#pragma unroll
      for (int r = 0; r < 16; ++r) {
        const int koff = (r & 3) + 8 * (r >> 2) + 4 * hi;
        if (koff > n) st[r] = -1e30f;
      }
    }
    float rs = 0.f;
#pragma unroll
    for (int r = 0; r < 16; ++r) { st[r] = __builtin_amdgcn_exp2f(st[r]); rs += st[r]; }
    l += rs;
    // pack this slab's P into the pending regs (pend PV already consumed old)
#pragma unroll
    for (int kk = 0; kk < 2; ++kk) {
      const int gown = (kk * 2 + hi) * 4, gsnd = (kk * 2 + (hi ^ 1)) * 4;
      u32 pa0 = pk2bf(st[gown + 0], st[gown + 1]);
      u32 pa1 = pk2bf(st[gown + 2], st[gown + 3]);
      u32 ps0 = pk2bf(st[gsnd + 0], st[gsnd + 1]);
      u32 ps1 = pk2bf(st[gsnd + 2], st[gsnd + 3]);
      u32 rA = __shfl_xor(ps0, 32, 64);
      u32 rB = __shfl_xor(ps1, 32, 64);
      U pb;
      pb.u[0] = hi ? rA : pa0;
      pb.u[1] = hi ? rB : pa1;
      pb.u[2] = hi ? pa0 : rA;
      pb.u[3] = hi ? pa1 : rB;
      if (kk == 0) pbP0 = pb.v; else pbP1 = pb.v;
    }
    // V fragments for this slab into pending regs (off the critical chain)
    const int c0 = ((mt * 4 + hi) << 4);
    const int c1 = ((mt * 4 + 2 + hi) << 4);
    vfP00 = *reinterpret_cast<const bf16x8*>(Vb + n * 128 + (c0 ^ sw0));
    vfP01 = *reinterpret_cast<const bf16x8*>(Vb + (32 + n) * 128 + (c0 ^ sw1));
    vfP10 = *reinterpret_cast<const bf16x8*>(Vb + n * 128 + (c1 ^ sw0));
    vfP11 = *reinterpret_cast<const bf16x8*>(Vb + (32 + n) * 128 + (c1 ^ sw1));
    pend = true;
  };

  for (int t = 0; t < ktiles; ++t) {
    // stage 2 ahead; clamp to last tile (dummy re-stage) so exactly 8 loads
    // are always outstanding -> vmcnt(4) is uniformly correct
    const int tpre = (t + 2 < ktiles) ? (t + 2) : (ktiles - 1);
    stage((t + 2) % 3, tpre);
    const char* Kb = (const char*)&Kls[t % 3][0];
    const char* Vb = (const char*)&Vls[t % 3][0];
    const int e0 = 2 * t;
    if (e0 <= jdiag) slab(Kb, Vb, 0, e0 == jdiag);
    if (e0 + 1 <= jdiag) slab(Kb, Vb, 1, e0 + 1 == jdiag);
    asm volatile("s_waitcnt vmcnt(4)" ::: "memory");
    __builtin_amdgcn_sched_barrier(0);
    __builtin_amdgcn_s_barrier();
    __builtin_amdgcn_sched_barrier(0);
  }

  // flush the last pending PV
  if (pend) {
    __builtin_amdgcn_s_setprio(1);
    o0 = __builtin_amdgcn_mfma_f32_32x32x16_bf16(vfP00, pbP0, o0, 0, 0, 0);
    o1 = __builtin_amdgcn_mfma_f32_32x32x16_bf16(vfP01, pbP0, o1, 0, 0, 0);
    o0 = __builtin_amdgcn_mfma_f32_32x32x16_bf16(vfP10, pbP1, o0, 0, 0, 0);
    o1 = __builtin_amdgcn_mfma_f32_32x32x16_bf16(vfP11, pbP1, o1, 0, 0, 0);
    __builtin_amdgcn_s_setprio(0);
  }

  // drain LDS-DMA before workgroup teardown (dummy stages may be in flight)
  asm volatile("s_waitcnt vmcnt(0)" ::: "memory");

  // ---- epilogue: O^T C-layout -> ob[b][s][h*64+d], normalize ----
  const int b = bh >> 4, h = bh & 15;
  const float lt = l + __shfl_xor(l, 32, 64);
  const float inv = 1.f / lt;
  const size_t rbase = ((size_t)(b * 2048 + q0w + n)) * 1024 + h * 64;
#pragma unroll
  for (int g = 0; g < 4; ++g) {
    ushort4 w0, w1;
    w0.x = f2bf(o0[g * 4 + 0] * inv); w0.y = f2bf(o0[g * 4 + 1] * inv);
    w0.z = f2bf(o0[g * 4 + 2] * inv); w0.w = f2bf(o0[g * 4 + 3] * inv);
    w1.x = f2bf(o1[g * 4 + 0] * inv); w1.y = f2bf(o1[g * 4 + 1] * inv);
    w1.z = f2bf(o1[g * 4 + 2] * inv); w1.w = f2bf(o1[g * 4 + 3] * inv);
    *reinterpret_cast<ushort4*>(&ob[rbase + g * 8 + hi * 4]) = w0;
    *reinterpret_cast<ushort4*>(&ob[rbase + 32 + g * 8 + hi * 4]) = w1;
  }
}

extern "C" void kernel_launch(void* const* d_in, const int* in_sizes, int n_in,
                              void* d_out, int out_size, void* d_ws, size_t ws_size,
                              hipStream_t stream) {
  const float* x     = (const float*)d_in[0];
  const float* Wqkv  = (const float*)d_in[1];
  const float* bqkv  = (const float*)d_in[2];
  const float* Wlift = (const float*)d_in[3];
  const float* blift = (const float*)d_in[4];
  float* out = (float*)d_out;

  if (ws_size < 40ull * 1024 * 1024) return;

  char* ws = (char*)d_ws;
  u16* xb     = (u16*)(ws);                        // 16 MB; reused as attn output
  u16* wqkvb  = (u16*)(ws + 16777216);             // 6 MB
  u16* wliftb = (u16*)(ws + 23068672);             // 2 MB
  u16* vT     = (u16*)(ws + 25165824);             // 16 MB
  u16* attnb  = xb;
  u16* qb = (u16*)d_out;                           // q/k in d_out (dead before lift GEMM)
  u16* kb = qb + 8388608;

  cast_all_kernel<<<12288, 256, 0, stream>>>(x, xb, Wqkv, wqkvb, Wlift, wliftb);

  gemm_bt_kernel<0><<<1536, 256, 0, stream>>>(
      xb, wqkvb, bqkv, qb, kb, vT, nullptr, 8192, 3072, 1024);

  attn_causal_kernel<<<1024, 256, 0, stream>>>(qb, kb, vT, attnb);

  gemm_bt_kernel<1><<<512, 256, 0, stream>>>(
      attnb, wliftb, blift, nullptr, nullptr, nullptr, out, 8192, 1024, 1024);
}